// Round 11
// baseline (261.234 us; speedup 1.0000x reference)
//
#include <hip/hip_runtime.h>

#define H 32
#define SEQ 512
#define BM 16          // batch rows per block (= MFMA N)
#define NTHREADS 512   // 8 waves; grid = 256 -> 1 block/CU, 2 waves/SIMD
#define HSTRIDE 40     // halves per h-row: 80B rows, 16B-aligned b128 frags

typedef _Float16 half8 __attribute__((ext_vector_type(8)));
typedef __attribute__((ext_vector_type(4))) float f32x4;

#define L2E 1.44269504088896340736f

__device__ __forceinline__ float rcp_(float x)  { return __builtin_amdgcn_rcpf(x); }
__device__ __forceinline__ float exp2_(float x) { return __builtin_amdgcn_exp2f(x); }  // raw v_exp_f32
#define MFMA16(A, B, C) __builtin_amdgcn_mfma_f32_16x16x32_f16((A), (B), (C), 0, 0, 0)

__global__ __launch_bounds__(NTHREADS, 2) void lstm_kernel(
    const float* __restrict__ x,      // [4096,512]
    const float* __restrict__ w_ih0,  // [128,1]
    const float* __restrict__ w_hh0,  // [128,32]
    const float* __restrict__ b_ih0, const float* __restrict__ b_hh0,
    const float* __restrict__ w_ih1,  // [128,32]
    const float* __restrict__ w_hh1,  // [128,32]
    const float* __restrict__ b_ih1, const float* __restrict__ b_hh1,
    const float* __restrict__ fc1_w,  // [16,32]
    const float* __restrict__ fc1_b,  // [16]
    const float* __restrict__ fc2_w,  // [1,16]
    const float* __restrict__ fc2_b,  // [1]
    float* __restrict__ out)          // [4096]
{
    __shared__ __align__(16) float    xbufT[SEQ * BM];            // 32 KB, [step][row]
    __shared__ __align__(16) _Float16 h1s[2][BM * HSTRIDE];       // ping-pong h1 (fp16)
    __shared__ __align__(16) _Float16 h2s[2][BM * HSTRIDE];       // ping-pong h2 (fp16)
    __shared__ __align__(16) float    h2f[BM * 33];
    __shared__ __align__(16) float    yb[BM * 17];

    const int tid  = threadIdx.x;
    const int lane = tid & 63;
    const int wv   = tid >> 6;          // wave id 0..7
    const int c    = lane & 15;         // frag free-index / batch col
    const int q    = lane >> 4;         // k-quad / D row-group
    const int r0   = blockIdx.x * BM;

    // ---- stage x transposed: xbufT[s][row] ----
    {
        const int row = tid >> 5;           // 0..15
        const int s0  = (tid & 31) * 16;    // 16 steps per thread
        const float* xr = x + (size_t)(r0 + row) * SEQ + s0;
        #pragma unroll
        for (int i = 0; i < 16; i += 4) {
            float4 v = *(const float4*)&xr[i];
            xbufT[(s0 + i + 0) * BM + row] = v.x;
            xbufT[(s0 + i + 1) * BM + row] = v.y;
            xbufT[(s0 + i + 2) * BM + row] = v.z;
            xbufT[(s0 + i + 3) * BM + row] = v.w;
        }
    }
    for (int i = tid; i < BM * HSTRIDE; i += NTHREADS) {
        h1s[0][i] = (_Float16)0.f; h1s[1][i] = (_Float16)0.f;
        h2s[0][i] = (_Float16)0.f; h2s[1][i] = (_Float16)0.f;
    }

    // ---- W fragments (A-operand), single fp16, rows permuted r -> (gate r&3, unit 4wv + r>>2)
    // gate scales folded (i,f,o: -L2E ; g: +2L2E) so EW uses raw v_exp_f32.
    const float gsc[4] = { -L2E, -L2E, 2.f * L2E, -L2E };
    const int worig = (c & 3) * H + 4 * wv + (c >> 2);
    const float wsc = gsc[c & 3];
    const int kb = 8 * q;
    half8 w0, wih, whh;
    {
        const float* p = &w_hh0[worig * H + kb];
        #pragma unroll
        for (int j = 0; j < 8; ++j) w0[j]  = (_Float16)(p[j] * wsc);
        p = &w_ih1[worig * H + kb];
        #pragma unroll
        for (int j = 0; j < 8; ++j) wih[j] = (_Float16)(p[j] * wsc);
        p = &w_hh1[worig * H + kb];
        #pragma unroll
        for (int j = 0; j < 8; ++j) whh[j] = (_Float16)(p[j] * wsc);
    }

    // per-lane cell: batch m = c, unit u = 4*wv + q
    const int m = c;
    const int u = 4 * wv + q;
    f32x4 bias1v, bias2v;
    float wx[4];
    #pragma unroll
    for (int g = 0; g < 4; ++g) {
        bias1v[g] = (b_ih0[g * H + u] + b_hh0[g * H + u]) * gsc[g];
        bias2v[g] = (b_ih1[g * H + u] + b_hh1[g * H + u]) * gsc[g];
        wx[g]     = w_ih0[g * H + u] * gsc[g];
    }
    const f32x4 zerov = {0.f, 0.f, 0.f, 0.f};   // loop-invariant C for the split g2 MFMA
    float cs1 = 0.f, cs2 = 0.f, h2last = 0.f;   // SCALED c-state: cs = 2*L2E*c

    const int fofs  = c * HSTRIDE + kb;   // b128 frag read offset (halves)
    const int whofs = m * HSTRIDE + u;    // h write offset (halves)

    __syncthreads();

    // LSTM cell in scaled-c domain (cs = 2*L2E*c): 5 v_exp + 2 v_rcp.
    // exp2 arg is cs directly (no mul on critical path); upper clamp only —
    // underflow (cs << 0) gives ec=0 -> h = -1/(1+eo), the correct tanh limit.
    auto cell = [&](const f32x4& g, float& cst) -> float {
        float ei = exp2_(g[0]), ef = exp2_(g[1]), eg = exp2_(g[2]), eo = exp2_(g[3]);
        float A  = 1.f + ei, F = 1.f + ef;
        float Gp = eg + 1.f, Gm = eg - 1.f;
        float t1 = A * Gp;
        float gmfs = (Gm * F) * (2.f * L2E);          // off-critical-path scale fold
        float num  = fmaf(cst, t1, gmfs);
        float csn  = num * rcp_(F * t1);
        cst = csn;
        float ec = exp2_(fminf(csn, 80.f));
        return (ec - 1.f) * rcp_((1.f + eo) * (ec + 1.f));
    };

    // iter t: L1 step t, L2 step t-1 (software-pipelined). One barrier/iter.
    auto do_step = [&](const _Float16* __restrict__ h1r, const _Float16* __restrict__ h2r,
                       _Float16* __restrict__ h1w, _Float16* __restrict__ h2w,
                       int t, bool e1, bool e2) {
        half8 a1 = *(const half8*)(h1r + fofs);
        half8 a2 = *(const half8*)(h2r + fofs);
        float xv = 0.f;
        if (e1) xv = xbufT[t * BM + m];
        // g1: 1-deep, C = bias; g2: two independent 1-deep MFMAs + add
        f32x4 g1  = MFMA16(w0,  a1, bias1v);
        f32x4 g2a = MFMA16(wih, a1, bias2v);
        f32x4 g2b = MFMA16(whh, a2, zerov);
        if (e1) {
            #pragma unroll
            for (int j = 0; j < 4; ++j) g1[j] = fmaf(xv, wx[j], g1[j]);
            float h1v = cell(g1, cs1);
            h1w[whofs] = (_Float16)h1v;     // write h1 the moment its chain ends
        }
        if (e2) {
            f32x4 g2;
            #pragma unroll
            for (int j = 0; j < 4; ++j) g2[j] = g2a[j] + g2b[j];
            float h2v = cell(g2, cs2);
            h2last = h2v;
            h2w[whofs] = (_Float16)h2v;
        }
        __syncthreads();
    };

    do_step(h1s[0], h2s[0], h1s[1], h2s[1], 0, true, false);
    for (int tt = 0; tt < 255; ++tt) {
        int t = 1 + 2 * tt;
        do_step(h1s[1], h2s[1], h1s[0], h2s[0], t,     true, true);
        do_step(h1s[0], h2s[0], h1s[1], h2s[1], t + 1, true, true);
    }
    do_step(h1s[1], h2s[1], h1s[0], h2s[0], 511, true, true);
    do_step(h1s[0], h2s[0], h1s[1], h2s[1], 512, false, true);

    // ---- FC head ----
    h2f[m * 33 + u] = h2last;
    __syncthreads();
    if (tid < BM * 16) {
        int rr = tid >> 4, j = tid & 15;
        float acc = fc1_b[j];
        #pragma unroll
        for (int k = 0; k < H; ++k) acc += fc1_w[j * H + k] * h2f[rr * 33 + k];
        acc = acc >= 0.f ? acc : 0.2f * acc;
        yb[rr * 17 + j] = acc * fc2_w[j];
    }
    __syncthreads();
    if (tid < BM) {
        float acc = fc2_b[0];
        #pragma unroll
        for (int j = 0; j < 16; ++j) acc += yb[tid * 17 + j];
        out[r0 + tid] = acc;
    }
}

extern "C" void kernel_launch(void* const* d_in, const int* in_sizes, int n_in,
                              void* d_out, int out_size, void* d_ws, size_t ws_size,
                              hipStream_t stream) {
    const float* x     = (const float*)d_in[0];
    const float* w_ih0 = (const float*)d_in[1];
    const float* w_hh0 = (const float*)d_in[2];
    const float* b_ih0 = (const float*)d_in[3];
    const float* b_hh0 = (const float*)d_in[4];
    const float* w_ih1 = (const float*)d_in[5];
    const float* w_hh1 = (const float*)d_in[6];
    const float* b_ih1 = (const float*)d_in[7];
    const float* b_hh1 = (const float*)d_in[8];
    const float* fc1_w = (const float*)d_in[9];
    const float* fc1_b = (const float*)d_in[10];
    const float* fc2_w = (const float*)d_in[11];
    const float* fc2_b = (const float*)d_in[12];
    float* out = (float*)d_out;

    const int B = in_sizes[0] / SEQ;   // 4096
    hipLaunchKernelGGL(lstm_kernel, dim3(B / BM), dim3(NTHREADS), 0, stream,
                       x, w_ih0, w_hh0, b_ih0, b_hh0, w_ih1, w_hh1, b_ih1, b_hh1,
                       fc1_w, fc1_b, fc2_w, fc2_b, out);
}

// Round 12
// 258.125 us; speedup vs baseline: 1.0120x; 1.0120x over previous
//
#include <hip/hip_runtime.h>

#define H 32
#define SEQ 512
#define BM 16          // batch rows per block (= MFMA N)
#define NTHREADS 512   // 8 waves; grid = 256 -> 1 block/CU, 2 waves/SIMD
#define HSTRIDE 40     // halves per h-row: 80B rows, 16B-aligned b128 frags

typedef _Float16 half8 __attribute__((ext_vector_type(8)));
typedef __attribute__((ext_vector_type(4))) float f32x4;

#define L2E 1.44269504088896340736f

__device__ __forceinline__ float rcp_(float x)  { return __builtin_amdgcn_rcpf(x); }
__device__ __forceinline__ float exp2_(float x) { return __builtin_amdgcn_exp2f(x); }  // raw v_exp_f32
#define MFMA16(A, B, C) __builtin_amdgcn_mfma_f32_16x16x32_f16((A), (B), (C), 0, 0, 0)

__global__ __launch_bounds__(NTHREADS, 2) void lstm_kernel(
    const float* __restrict__ x,      // [4096,512]
    const float* __restrict__ w_ih0,  // [128,1]
    const float* __restrict__ w_hh0,  // [128,32]
    const float* __restrict__ b_ih0, const float* __restrict__ b_hh0,
    const float* __restrict__ w_ih1,  // [128,32]
    const float* __restrict__ w_hh1,  // [128,32]
    const float* __restrict__ b_ih1, const float* __restrict__ b_hh1,
    const float* __restrict__ fc1_w,  // [16,32]
    const float* __restrict__ fc1_b,  // [16]
    const float* __restrict__ fc2_w,  // [1,16]
    const float* __restrict__ fc2_b,  // [1]
    float* __restrict__ out)          // [4096]
{
    __shared__ __align__(16) float    xbufT[SEQ * BM];            // 32 KB, [step][row]
    __shared__ __align__(16) _Float16 h1s[2][BM * HSTRIDE];       // ping-pong h1 (fp16)
    __shared__ __align__(16) _Float16 h2s[2][BM * HSTRIDE];       // ping-pong h2 (fp16)
    __shared__ __align__(16) float    h2f[BM * 33];
    __shared__ __align__(16) float    yb[BM * 17];

    const int tid  = threadIdx.x;
    const int lane = tid & 63;
    const int wv   = tid >> 6;          // wave id 0..7
    const int c    = lane & 15;         // frag free-index / batch col
    const int q    = lane >> 4;         // k-quad / D row-group
    const int r0   = blockIdx.x * BM;

    // ---- stage x transposed: xbufT[s][row] ----
    {
        const int row = tid >> 5;           // 0..15
        const int s0  = (tid & 31) * 16;    // 16 steps per thread
        const float* xr = x + (size_t)(r0 + row) * SEQ + s0;
        #pragma unroll
        for (int i = 0; i < 16; i += 4) {
            float4 v = *(const float4*)&xr[i];
            xbufT[(s0 + i + 0) * BM + row] = v.x;
            xbufT[(s0 + i + 1) * BM + row] = v.y;
            xbufT[(s0 + i + 2) * BM + row] = v.z;
            xbufT[(s0 + i + 3) * BM + row] = v.w;
        }
    }
    for (int i = tid; i < BM * HSTRIDE; i += NTHREADS) {
        h1s[0][i] = (_Float16)0.f; h1s[1][i] = (_Float16)0.f;
        h2s[0][i] = (_Float16)0.f; h2s[1][i] = (_Float16)0.f;
    }

    // ---- W fragments (A-operand), single fp16, rows permuted r -> (gate r&3, unit 4wv + r>>2)
    // gate scales folded (i,f,o: -L2E ; g: +2L2E) so EW uses raw v_exp_f32.
    const float gsc[4] = { -L2E, -L2E, 2.f * L2E, -L2E };
    const int worig = (c & 3) * H + 4 * wv + (c >> 2);
    const float wsc = gsc[c & 3];
    const int kb = 8 * q;
    half8 w0, wih, whh;
    {
        const float* p = &w_hh0[worig * H + kb];
        #pragma unroll
        for (int j = 0; j < 8; ++j) w0[j]  = (_Float16)(p[j] * wsc);
        p = &w_ih1[worig * H + kb];
        #pragma unroll
        for (int j = 0; j < 8; ++j) wih[j] = (_Float16)(p[j] * wsc);
        p = &w_hh1[worig * H + kb];
        #pragma unroll
        for (int j = 0; j < 8; ++j) whh[j] = (_Float16)(p[j] * wsc);
    }

    // per-lane cell: batch m = c, unit u = 4*wv + q
    const int m = c;
    const int u = 4 * wv + q;
    f32x4 bias1v, bias2v;
    float wx[4];
    #pragma unroll
    for (int g = 0; g < 4; ++g) {
        bias1v[g] = (b_ih0[g * H + u] + b_hh0[g * H + u]) * gsc[g];
        bias2v[g] = (b_ih1[g * H + u] + b_hh1[g * H + u]) * gsc[g];
        wx[g]     = w_ih0[g * H + u] * gsc[g];
    }
    float c1 = 0.f, c2 = 0.f, h2last = 0.f;

    const int fofs  = c * HSTRIDE + kb;   // b128 frag read offset (halves)
    const int whofs = m * HSTRIDE + u;    // h write offset (halves)

    __syncthreads();

    // LSTM cell: 5 v_exp + 2 v_rcp (R10-exact numerics)
    auto cell = [&](const f32x4& g, float& cst) -> float {
        float ei = exp2_(g[0]), ef = exp2_(g[1]), eg = exp2_(g[2]), eo = exp2_(g[3]);
        float A  = 1.f + ei, F = 1.f + ef;
        float Gp = eg + 1.f, Gm = eg - 1.f;
        float t1 = A * Gp;
        float num = fmaf(cst, t1, Gm * F);
        float cn  = num * rcp_(F * t1);
        cst = cn;
        float ec = exp2_(fminf(cn * (2.f * L2E), 80.f));
        return (ec - 1.f) * rcp_((1.f + eo) * (ec + 1.f));
    };

    // Lag-2 pipeline: iter t computes L1 step t and L2 step t-2.
    //   L1: needs h1(t-1)  -> ds_read (critical path)
    //   L2: needs h1(t-2)  -> a1prev register (the a1 frag read at iter t-1; NO ds_read)
    //       needs h2(t-3)  -> ds_read, no deadline (slack work in L1's latency shadow)
    half8 a1prev = {};   // zero-init; first consumed at t=2 as h1(0) saved at t=1
    auto do_step = [&](const _Float16* __restrict__ h1r, const _Float16* __restrict__ h2r,
                       _Float16* __restrict__ h1w, _Float16* __restrict__ h2w,
                       int t, bool e1, bool e2) {
        half8 a1  = *(const half8*)(h1r + fofs);   // h1(t-1)
        half8 a2o = *(const half8*)(h2r + fofs);   // h2(t-3)
        if (e1) {
            float xv = xbufT[t * BM + m];
            f32x4 g1 = MFMA16(w0, a1, bias1v);
            #pragma unroll
            for (int j = 0; j < 4; ++j) g1[j] = fmaf(xv, wx[j], g1[j]);
            float h1v = cell(g1, c1);
            h1w[whofs] = (_Float16)h1v;            // critical-path write
        }
        if (e2) {
            // all inputs available at iteration start; fully off-critical
            f32x4 g2 = MFMA16(whh, a2o, MFMA16(wih, a1prev, bias2v));
            float h2v = cell(g2, c2);
            h2last = h2v;
            h2w[whofs] = (_Float16)h2v;
        }
        a1prev = a1;                               // carry h1(t-1) for next iter's L2
        __syncthreads();
    };

    // t=0..513 (514 iters). e1 = t<512, e2 = t>=2. Write buf[t&1], read buf[(t+1)&1].
    do_step(h1s[1], h2s[1], h1s[0], h2s[0], 0, true, false);
    do_step(h1s[0], h2s[0], h1s[1], h2s[1], 1, true, false);
    for (int tt = 0; tt < 255; ++tt) {
        int t = 2 + 2 * tt;
        do_step(h1s[1], h2s[1], h1s[0], h2s[0], t,     true, true);
        do_step(h1s[0], h2s[0], h1s[1], h2s[1], t + 1, true, true);
    }
    do_step(h1s[1], h2s[1], h1s[0], h2s[0], 512, false, true);
    do_step(h1s[0], h2s[0], h1s[1], h2s[1], 513, false, true);

    // ---- FC head ----
    h2f[m * 33 + u] = h2last;
    __syncthreads();
    if (tid < BM * 16) {
        int rr = tid >> 4, j = tid & 15;
        float acc = fc1_b[j];
        #pragma unroll
        for (int k = 0; k < H; ++k) acc += fc1_w[j * H + k] * h2f[rr * 33 + k];
        acc = acc >= 0.f ? acc : 0.2f * acc;
        yb[rr * 17 + j] = acc * fc2_w[j];
    }
    __syncthreads();
    if (tid < BM) {
        float acc = fc2_b[0];
        #pragma unroll
        for (int j = 0; j < 16; ++j) acc += yb[tid * 17 + j];
        out[r0 + tid] = acc;
    }
}

extern "C" void kernel_launch(void* const* d_in, const int* in_sizes, int n_in,
                              void* d_out, int out_size, void* d_ws, size_t ws_size,
                              hipStream_t stream) {
    const float* x     = (const float*)d_in[0];
    const float* w_ih0 = (const float*)d_in[1];
    const float* w_hh0 = (const float*)d_in[2];
    const float* b_ih0 = (const float*)d_in[3];
    const float* b_hh0 = (const float*)d_in[4];
    const float* w_ih1 = (const float*)d_in[5];
    const float* w_hh1 = (const float*)d_in[6];
    const float* b_ih1 = (const float*)d_in[7];
    const float* b_hh1 = (const float*)d_in[8];
    const float* fc1_w = (const float*)d_in[9];
    const float* fc1_b = (const float*)d_in[10];
    const float* fc2_w = (const float*)d_in[11];
    const float* fc2_b = (const float*)d_in[12];
    float* out = (float*)d_out;

    const int B = in_sizes[0] / SEQ;   // 4096
    hipLaunchKernelGGL(lstm_kernel, dim3(B / BM), dim3(NTHREADS), 0, stream,
                       x, w_ih0, w_hh0, b_ih0, b_hh0, w_ih1, w_hh1, b_ih1, b_hh1,
                       fc1_w, fc1_b, fc2_w, fc2_b, out);
}